// Round 1
// baseline (678.664 us; speedup 1.0000x reference)
//
#include <hip/hip_runtime.h>
#include <math.h>

#define N 8192
#define FDIM 512
#define H 64
#define NEG_BIAS -9.0f
#define MAXE 2048

// ---------------- K1: fts = features @ W  (8192x512 @ 512x64) ----------------
__global__ __launch_bounds__(256) void k_fts(const float* __restrict__ feat,
                                             const float* __restrict__ W,
                                             float* __restrict__ fts) {
    __shared__ float Af[64][65];   // padded
    __shared__ float Bf[64][64];
    int t = threadIdx.x;
    int row0 = blockIdx.x * 64;
    int hq = (t & 15) * 4;     // 4 h columns
    int rq = (t >> 4) * 4;     // 4 rows
    float acc[4][4] = {};
    for (int k0 = 0; k0 < FDIM; k0 += 64) {
#pragma unroll
        for (int i = 0; i < 4; ++i) {
            int l = t + i * 256;        // 0..1023 float4 slots
            int r = l >> 4;             // 0..63
            int c4 = (l & 15) * 4;
            float4 av = *(const float4*)&feat[(size_t)(row0 + r) * FDIM + k0 + c4];
            Af[r][c4 + 0] = av.x; Af[r][c4 + 1] = av.y;
            Af[r][c4 + 2] = av.z; Af[r][c4 + 3] = av.w;
            float4 bv = *(const float4*)&W[(size_t)(k0 + r) * H + c4];
            *(float4*)&Bf[r][c4] = bv;
        }
        __syncthreads();
#pragma unroll 8
        for (int kk = 0; kk < 64; ++kk) {
            float a[4];
#pragma unroll
            for (int j = 0; j < 4; ++j) a[j] = Af[rq + j][kk];
            float4 b = *(const float4*)&Bf[kk][hq];
#pragma unroll
            for (int j = 0; j < 4; ++j) {
                acc[j][0] += a[j] * b.x;
                acc[j][1] += a[j] * b.y;
                acc[j][2] += a[j] * b.z;
                acc[j][3] += a[j] * b.w;
            }
        }
        __syncthreads();
    }
#pragma unroll
    for (int j = 0; j < 4; ++j) {
        float4 v = make_float4(acc[j][0], acc[j][1], acc[j][2], acc[j][3]);
        *(float4*)&fts[(size_t)(row0 + rq + j) * H + hq] = v;
    }
}

// ---------------- K1b: f1 = fts.a1 + b1, f2 = fts.a2 + b2 ----------------
__global__ __launch_bounds__(256) void k_f12(const float* __restrict__ fts,
                                             const float* __restrict__ a1, const float* __restrict__ b1,
                                             const float* __restrict__ a2, const float* __restrict__ b2,
                                             float* __restrict__ f1, float* __restrict__ f2) {
    int t = threadIdx.x;
    int lane = t & 63;
    int m = blockIdx.x * 4 + (t >> 6);
    float v = fts[(size_t)m * H + lane];
    float s1 = v * a1[lane];
    float s2 = v * a2[lane];
#pragma unroll
    for (int o = 32; o; o >>= 1) { s1 += __shfl_xor(s1, o); s2 += __shfl_xor(s2, o); }
    if (lane == 0) { f1[m] = s1 + b1[0]; f2[m] = s2 + b2[0]; }
}

// ---------------- K2: bitonic sort of f2 (ascending), with permutation ----------------
__global__ __launch_bounds__(1024) void k_sort(const float* __restrict__ f2,
                                               float* __restrict__ f2s, int* __restrict__ perm) {
    extern __shared__ char smem[];
    float* key = (float*)smem;
    int* idx = (int*)(smem + N * sizeof(float));
    int t = threadIdx.x;
    for (int i = t; i < N; i += 1024) { key[i] = f2[i]; idx[i] = i; }
    __syncthreads();
    for (int k = 2; k <= N; k <<= 1) {
        for (int j = k >> 1; j > 0; j >>= 1) {
            for (int i = t; i < N; i += 1024) {
                int ij = i ^ j;
                if (ij > i) {
                    bool up = ((i & k) == 0);
                    float ki = key[i], kj = key[ij];
                    bool sw = up ? (ki > kj) : (ki < kj);
                    if (sw) {
                        key[i] = kj; key[ij] = ki;
                        int tmp = idx[i]; idx[i] = idx[ij]; idx[ij] = tmp;
                    }
                }
            }
            __syncthreads();
        }
    }
    for (int i = t; i < N; i += 1024) { f2s[i] = key[i]; perm[i] = idx[i]; }
}

// ---------------- K3: suffix-sum tables over sorted order ----------------
// SufF[k][h] = sum_{pos>=k} fts[perm[pos]][h]
// SufQ[k][h] = sum_{pos>=k} exp(f2s[pos]) * fts[perm[pos]][h]
// SufE[k]    = sum_{pos>=k} exp(f2s[pos])
__global__ __launch_bounds__(256) void k_scan(const float* __restrict__ fts,
                                              const float* __restrict__ f2s,
                                              const int* __restrict__ perm,
                                              float* __restrict__ SufF,
                                              float* __restrict__ SufQ,
                                              float* __restrict__ SufE) {
    __shared__ float chF[256], chQ[256], exF[256], exQ[256];
    int t = threadIdx.x;
    int h = blockIdx.x;
    int base = t * 32;
    if (h < H) {
        float sF = 0.f, sQ = 0.f;
        for (int i = 0; i < 32; ++i) {
            int pos = base + i;
            float g = fts[(size_t)perm[pos] * H + h];
            sF += g;
            sQ += __expf(f2s[pos]) * g;
        }
        chF[t] = sF; chQ[t] = sQ;
        __syncthreads();
        if (t == 0) {
            float rF = 0.f, rQ = 0.f;
            for (int tt = 255; tt >= 0; --tt) {
                exF[tt] = rF; exQ[tt] = rQ;
                rF += chF[tt]; rQ += chQ[tt];
            }
        }
        __syncthreads();
        float suF = exF[t], suQ = exQ[t];
        for (int i = 31; i >= 0; --i) {
            int pos = base + i;
            float g = fts[(size_t)perm[pos] * H + h];
            suF += g;
            suQ += __expf(f2s[pos]) * g;
            SufF[(size_t)pos * H + h] = suF;
            SufQ[(size_t)pos * H + h] = suQ;
        }
        if (t == 0) { SufF[(size_t)N * H + h] = 0.f; SufQ[(size_t)N * H + h] = 0.f; }
    } else {
        float s = 0.f;
        for (int i = 0; i < 32; ++i) s += __expf(f2s[base + i]);
        chF[t] = s;
        __syncthreads();
        if (t == 0) {
            float r = 0.f;
            for (int tt = 255; tt >= 0; --tt) { exF[tt] = r; r += chF[tt]; }
        }
        __syncthreads();
        float su = exF[t];
        for (int i = 31; i >= 0; --i) { su += __expf(f2s[base + i]); SufE[base + i] = su; }
        if (t == 0) SufE[N] = 0.f;
    }
}

// ---------------- K4: main pass — scan bias row, edge accumulate, combine ----------------
__global__ __launch_bounds__(256) void k_main(const float* __restrict__ bias,
                                              const float* __restrict__ fts,
                                              const float* __restrict__ f1g,
                                              const float* __restrict__ f2g,
                                              const float* __restrict__ f2s,
                                              const float* __restrict__ SufF,
                                              const float* __restrict__ SufQ,
                                              const float* __restrict__ SufE,
                                              float* __restrict__ out) {
    __shared__ int listN[MAXE];
    __shared__ float listF[MAXE];
    __shared__ float redW[4][64], redF[4][64], redE[4];
    __shared__ int s_cnt, s_k;
    int t = threadIdx.x;
    int m = blockIdx.x;
    float f1m = f1g[m];
    if (t == 0) {
        s_cnt = 0;
        float thr = -f1m;
        int lo = 0, hi = N;
        while (lo < hi) { int mid = (lo + hi) >> 1; if (f2s[mid] > thr) hi = mid; else lo = mid + 1; }
        s_k = lo;
    }
    __syncthreads();
    // Phase A: stream bias row, collect edges (bias == 0)
    const float4* brow = (const float4*)(bias + (size_t)m * N);
#pragma unroll
    for (int i = 0; i < 8; ++i) {
        int sl = t + i * 256;
        float4 b4 = brow[sl];
        int nb = sl * 4;
        if (b4.x == 0.f) { int p = atomicAdd(&s_cnt, 1); if (p < MAXE) { listN[p] = nb;     listF[p] = f2g[nb];     } }
        if (b4.y == 0.f) { int p = atomicAdd(&s_cnt, 1); if (p < MAXE) { listN[p] = nb + 1; listF[p] = f2g[nb + 1]; } }
        if (b4.z == 0.f) { int p = atomicAdd(&s_cnt, 1); if (p < MAXE) { listN[p] = nb + 2; listF[p] = f2g[nb + 2]; } }
        if (b4.w == 0.f) { int p = atomicAdd(&s_cnt, 1); if (p < MAXE) { listN[p] = nb + 3; listF[p] = f2g[nb + 3]; } }
    }
    __syncthreads();
    int cnt = s_cnt < MAXE ? s_cnt : MAXE;
    int k = s_k;
    // Phase B: edge accumulation, wave w handles edges w, w+4, ... ; lane = h
    int w = t >> 6, lane = t & 63;
    float accW = 0.f, accF = 0.f, accE = 0.f;
    int e = w;
    float ffc = 0.f, vc = 0.f;
    if (e < cnt) { int n = listN[e]; ffc = listF[e]; vc = fts[(size_t)n * H + lane]; }
    while (e < cnt) {
        int e2 = e + 4;
        float ffn = 0.f, vn = 0.f;
        if (e2 < cnt) { int n2 = listN[e2]; ffn = listF[e2]; vn = fts[(size_t)n2 * H + lane]; }
        float ee = __expf(fmaxf(f1m + ffc, 0.f));
        accW += ee * vc;
        accF += vc;
        accE += ee;
        ffc = ffn; vc = vn; e = e2;
    }
    redW[w][lane] = accW;
    redF[w][lane] = accF;
    if (lane == 0) redE[w] = accE;
    __syncthreads();
    if (t < 64) {
        int h = t;
        float eW = redW[0][h] + redW[1][h] + redW[2][h] + redW[3][h];
        float eF = redF[0][h] + redF[1][h] + redF[2][h] + redF[3][h];
        float eE = redE[0] + redE[1] + redE[2] + redE[3];
        float T  = SufF[h];                    // k = 0 row: total column sum
        float P  = SufF[(size_t)k * H + h];
        float Q  = SufQ[(size_t)k * H + h];
        float Es = SufE[k];
        float ef1 = __expf(f1m);
        const float c = 1.2340980408667956e-4f;  // exp(-9)
        float nLE = (float)k;                   // count of x <= 0
        float denseW = (T - P) + ef1 * Q;       // sum_all e_n * fts
        float denseE = nLE + ef1 * Es;          // sum_all e_n
        float D = c * denseE + (1.f - c) * eE;
        float S = (c * denseW + (1.f - c) * eW) / D;
        float val = S + NEG_BIAS * (T - eF);
        out[(size_t)m * H + h] = val > 0.f ? val : expm1f(val);
    }
}

extern "C" void kernel_launch(void* const* d_in, const int* in_sizes, int n_in,
                              void* d_out, int out_size, void* d_ws, size_t ws_size,
                              hipStream_t stream) {
    const float* feat = (const float*)d_in[0];
    const float* bias = (const float*)d_in[1];
    const float* W    = (const float*)d_in[2];
    const float* a1   = (const float*)d_in[3];
    const float* b1   = (const float*)d_in[4];
    const float* a2   = (const float*)d_in[5];
    const float* b2   = (const float*)d_in[6];
    float* out = (float*)d_out;

    float* ws   = (float*)d_ws;
    float* fts  = ws;                       // N*H          = 524288
    float* f1   = fts + (size_t)N * H;      // N
    float* f2   = f1 + N;                   // N
    float* f2s  = f2 + N;                   // N
    int*   perm = (int*)(f2s + N);          // N
    float* SufF = (float*)(perm + N);       // (N+1)*H
    float* SufQ = SufF + (size_t)(N + 1) * H;
    float* SufE = SufQ + (size_t)(N + 1) * H;   // N+1

    hipLaunchKernelGGL(k_fts,  dim3(N / 64), dim3(256), 0, stream, feat, W, fts);
    hipLaunchKernelGGL(k_f12,  dim3(N / 4),  dim3(256), 0, stream, fts, a1, b1, a2, b2, f1, f2);
    hipLaunchKernelGGL(k_sort, dim3(1), dim3(1024), N * 8, stream, f2, f2s, perm);
    hipLaunchKernelGGL(k_scan, dim3(H + 1), dim3(256), 0, stream, fts, f2s, perm, SufF, SufQ, SufE);
    hipLaunchKernelGGL(k_main, dim3(N), dim3(256), 0, stream, bias, fts, f1, f2, f2s, SufF, SufQ, SufE, out);
}

// Round 2
// 419.682 us; speedup vs baseline: 1.6171x; 1.6171x over previous
//
#include <hip/hip_runtime.h>
#include <math.h>

#define N 8192
#define FDIM 512
#define H 64
#define MAXE 512

// ---------------- K1: fts = features @ W, plus column sums T[h] ----------------
__global__ __launch_bounds__(256) void k_fts(const float* __restrict__ feat,
                                             const float* __restrict__ W,
                                             float* __restrict__ fts,
                                             float* __restrict__ T) {
    __shared__ float Af[64][65];   // padded
    __shared__ float Bf[64][64];
    __shared__ float colred[16][64];
    int t = threadIdx.x;
    int row0 = blockIdx.x * 64;
    int hq = (t & 15) * 4;     // 4 h columns
    int rq = (t >> 4) * 4;     // 4 rows
    float acc[4][4] = {};
    for (int k0 = 0; k0 < FDIM; k0 += 64) {
#pragma unroll
        for (int i = 0; i < 4; ++i) {
            int l = t + i * 256;        // 0..1023 float4 slots
            int r = l >> 4;             // 0..63
            int c4 = (l & 15) * 4;
            float4 av = *(const float4*)&feat[(size_t)(row0 + r) * FDIM + k0 + c4];
            Af[r][c4 + 0] = av.x; Af[r][c4 + 1] = av.y;
            Af[r][c4 + 2] = av.z; Af[r][c4 + 3] = av.w;
            float4 bv = *(const float4*)&W[(size_t)(k0 + r) * H + c4];
            *(float4*)&Bf[r][c4] = bv;
        }
        __syncthreads();
#pragma unroll 8
        for (int kk = 0; kk < 64; ++kk) {
            float a[4];
#pragma unroll
            for (int j = 0; j < 4; ++j) a[j] = Af[rq + j][kk];
            float4 b = *(const float4*)&Bf[kk][hq];
#pragma unroll
            for (int j = 0; j < 4; ++j) {
                acc[j][0] += a[j] * b.x;
                acc[j][1] += a[j] * b.y;
                acc[j][2] += a[j] * b.z;
                acc[j][3] += a[j] * b.w;
            }
        }
        __syncthreads();
    }
#pragma unroll
    for (int j = 0; j < 4; ++j) {
        float4 v = make_float4(acc[j][0], acc[j][1], acc[j][2], acc[j][3]);
        *(float4*)&fts[(size_t)(row0 + rq + j) * H + hq] = v;
    }
    // block-level column sums -> global T via atomicAdd (T pre-zeroed by memset)
#pragma unroll
    for (int i = 0; i < 4; ++i)
        colred[t >> 4][hq + i] = acc[0][i] + acc[1][i] + acc[2][i] + acc[3][i];
    __syncthreads();
    if (t < H) {
        float s = 0.f;
#pragma unroll
        for (int g = 0; g < 16; ++g) s += colred[g][t];
        atomicAdd(&T[t], s);
    }
}

// ---------------- K1b: f1 = fts.a1 + b1, f2 = fts.a2 + b2 ----------------
__global__ __launch_bounds__(256) void k_f12(const float* __restrict__ fts,
                                             const float* __restrict__ a1, const float* __restrict__ b1,
                                             const float* __restrict__ a2, const float* __restrict__ b2,
                                             float* __restrict__ f1, float* __restrict__ f2) {
    int t = threadIdx.x;
    int lane = t & 63;
    int m = blockIdx.x * 4 + (t >> 6);
    float v = fts[(size_t)m * H + lane];
    float s1 = v * a1[lane];
    float s2 = v * a2[lane];
#pragma unroll
    for (int o = 32; o; o >>= 1) { s1 += __shfl_xor(s1, o); s2 += __shfl_xor(s2, o); }
    if (lane == 0) { f1[m] = s1 + b1[0]; f2[m] = s2 + b2[0]; }
}

// ---------------- K2: main pass — stream bias row, ballot-compact edges, accumulate ----------------
__global__ __launch_bounds__(256) void k_main(const float* __restrict__ bias,
                                              const float* __restrict__ fts,
                                              const float* __restrict__ f1g,
                                              const float* __restrict__ f2g,
                                              const float* __restrict__ T,
                                              float* __restrict__ out) {
    __shared__ int   listN[MAXE];
    __shared__ float listF[MAXE];
    __shared__ float redW[8][64];
    __shared__ float redF[8][64];
    __shared__ float redE[8];
    __shared__ int s_cnt;
    const int t = threadIdx.x;
    const int m = blockIdx.x;
    const int lane = t & 63;
    const int w = t >> 6;
    if (t == 0) s_cnt = 0;
    __syncthreads();
    const float f1m = f1g[m];

    // Phase A: hoisted loads (full MLP), then ballot compaction of edge columns
    const float4* brow = (const float4*)(bias + (size_t)m * N);
    float4 r[8];
#pragma unroll
    for (int i = 0; i < 8; ++i) r[i] = brow[t + i * 256];
    const unsigned long long lmask = (1ULL << lane) - 1ULL;
#pragma unroll
    for (int i = 0; i < 8; ++i) {
        int nb = (t + i * 256) * 4;
        float c0 = r[i].x, c1 = r[i].y, c2 = r[i].z, c3 = r[i].w;
#pragma unroll
        for (int q = 0; q < 4; ++q) {
            float cv = q == 0 ? c0 : q == 1 ? c1 : q == 2 ? c2 : c3;
            bool is_edge = (cv == 0.f);
            unsigned long long mb = __ballot(is_edge);
            int base = 0;
            if (lane == 0) base = atomicAdd(&s_cnt, (int)__popcll(mb));
            base = __shfl(base, 0);
            if (is_edge) {
                int idx = base + (int)__popcll(mb & lmask);
                if (idx < MAXE) listN[idx] = nb + q;
            }
        }
    }
    __syncthreads();
    const int cnt = s_cnt < MAXE ? s_cnt : MAXE;
    for (int j = t; j < cnt; j += 256) listF[j] = f2g[listN[j]];
    __syncthreads();

    // Phase B: 8 concurrent edge streams (half-wave granularity, float2 over h)
    const int sub = lane >> 5;          // 0/1 within wave
    const int hh = (lane & 31) * 2;     // h pair
    const int slot = w * 2 + sub;       // 0..7
    float aWx = 0.f, aWy = 0.f, aFx = 0.f, aFy = 0.f, aE = 0.f;
    int e = slot;
    float ff0 = 0.f; float2 v0 = make_float2(0.f, 0.f);
    if (e < cnt) { ff0 = listF[e]; v0 = *(const float2*)&fts[(size_t)listN[e] * H + hh]; }
    while (e < cnt) {
        int e1 = e + 8;
        float ff1 = 0.f; float2 v1 = make_float2(0.f, 0.f);
        if (e1 < cnt) { ff1 = listF[e1]; v1 = *(const float2*)&fts[(size_t)listN[e1] * H + hh]; }
        float ee = __expf(fmaxf(f1m + ff0, 0.f));
        aWx += ee * v0.x; aWy += ee * v0.y;
        aFx += v0.x;      aFy += v0.y;
        aE += ee;
        ff0 = ff1; v0 = v1; e = e1;
    }
    redW[slot][hh] = aWx; redW[slot][hh + 1] = aWy;
    redF[slot][hh] = aFx; redF[slot][hh + 1] = aFy;
    if ((lane & 31) == 0) redE[slot] = aE;
    __syncthreads();

    if (t < H) {
        float eW = 0.f, eF = 0.f, eE = 0.f;
#pragma unroll
        for (int s = 0; s < 8; ++s) { eW += redW[s][t]; eF += redF[s][t]; eE += redE[s]; }
        float S = (cnt > 0) ? eW / eE : 0.f;
        float val = S - 9.0f * (T[t] - eF);
        out[(size_t)m * H + t] = val > 0.f ? val : expm1f(val);
    }
}

extern "C" void kernel_launch(void* const* d_in, const int* in_sizes, int n_in,
                              void* d_out, int out_size, void* d_ws, size_t ws_size,
                              hipStream_t stream) {
    const float* feat = (const float*)d_in[0];
    const float* bias = (const float*)d_in[1];
    const float* W    = (const float*)d_in[2];
    const float* a1   = (const float*)d_in[3];
    const float* b1   = (const float*)d_in[4];
    const float* a2   = (const float*)d_in[5];
    const float* b2   = (const float*)d_in[6];
    float* out = (float*)d_out;

    float* ws   = (float*)d_ws;
    float* fts  = ws;                       // N*H
    float* f1   = fts + (size_t)N * H;      // N
    float* f2   = f1 + N;                   // N
    float* T    = f2 + N;                   // H

    hipMemsetAsync(T, 0, H * sizeof(float), stream);
    hipLaunchKernelGGL(k_fts,  dim3(N / 64), dim3(256), 0, stream, feat, W, fts, T);
    hipLaunchKernelGGL(k_f12,  dim3(N / 4),  dim3(256), 0, stream, fts, a1, b1, a2, b2, f1, f2);
    hipLaunchKernelGGL(k_main, dim3(N), dim3(256), 0, stream, bias, fts, f1, f2, T, out);
}

// Round 3
// 400.956 us; speedup vs baseline: 1.6926x; 1.0467x over previous
//
#include <hip/hip_runtime.h>
#include <math.h>

#define N 8192
#define FDIM 512
#define H 64
#define MAXE 512

// ---- K1: fts = feat @ W  (+ fused f1/f2 row dots, + column sums T) ----
// 32 rows per block, 256 blocks -> all CUs busy.
__global__ __launch_bounds__(256) void k_fts(const float* __restrict__ feat,
                                             const float* __restrict__ W,
                                             const float* __restrict__ a1v,
                                             const float* __restrict__ b1v,
                                             const float* __restrict__ a2v,
                                             const float* __restrict__ b2v,
                                             float* __restrict__ fts,
                                             float* __restrict__ f1,
                                             float* __restrict__ f2,
                                             float* __restrict__ T) {
    __shared__ float Af[32][65];       // padded
    __shared__ float Bf[64][64];
    __shared__ float colred[16][64];
    const int t = threadIdx.x;
    const int row0 = blockIdx.x * 32;
    const int hq = (t & 15) * 4;       // 4 h columns
    const int rq = (t >> 4) * 2;       // 2 rows
    float acc[2][4] = {};
    for (int k0 = 0; k0 < FDIM; k0 += 64) {
#pragma unroll
        for (int i = 0; i < 2; ++i) {          // A tile: 32x64 = 512 float4
            int l = t + i * 256;
            int r = l >> 4;
            int c4 = (l & 15) * 4;
            float4 av = *(const float4*)&feat[(size_t)(row0 + r) * FDIM + k0 + c4];
            Af[r][c4 + 0] = av.x; Af[r][c4 + 1] = av.y;
            Af[r][c4 + 2] = av.z; Af[r][c4 + 3] = av.w;
        }
#pragma unroll
        for (int i = 0; i < 4; ++i) {          // B tile: 64x64 = 1024 float4
            int l = t + i * 256;
            int r = l >> 4;
            int c4 = (l & 15) * 4;
            *(float4*)&Bf[r][c4] = *(const float4*)&W[(size_t)(k0 + r) * H + c4];
        }
        __syncthreads();
#pragma unroll 8
        for (int kk = 0; kk < 64; ++kk) {
            float a0 = Af[rq][kk];
            float a1_ = Af[rq + 1][kk];
            float4 b = *(const float4*)&Bf[kk][hq];
            acc[0][0] += a0 * b.x;  acc[0][1] += a0 * b.y;
            acc[0][2] += a0 * b.z;  acc[0][3] += a0 * b.w;
            acc[1][0] += a1_ * b.x; acc[1][1] += a1_ * b.y;
            acc[1][2] += a1_ * b.z; acc[1][3] += a1_ * b.w;
        }
        __syncthreads();
    }
#pragma unroll
    for (int j = 0; j < 2; ++j) {
        float4 v = make_float4(acc[j][0], acc[j][1], acc[j][2], acc[j][3]);
        *(float4*)&fts[(size_t)(row0 + rq + j) * H + hq] = v;
    }
    // fused f1/f2: dot over h within each 16-lane group
    float pa1[4], pa2[4];
#pragma unroll
    for (int i = 0; i < 4; ++i) { pa1[i] = a1v[hq + i]; pa2[i] = a2v[hq + i]; }
#pragma unroll
    for (int j = 0; j < 2; ++j) {
        float s1 = acc[j][0] * pa1[0] + acc[j][1] * pa1[1] + acc[j][2] * pa1[2] + acc[j][3] * pa1[3];
        float s2 = acc[j][0] * pa2[0] + acc[j][1] * pa2[1] + acc[j][2] * pa2[2] + acc[j][3] * pa2[3];
#pragma unroll
        for (int o = 8; o; o >>= 1) { s1 += __shfl_xor(s1, o); s2 += __shfl_xor(s2, o); }
        if ((t & 15) == 0) {
            f1[row0 + rq + j] = s1 + b1v[0];
            f2[row0 + rq + j] = s2 + b2v[0];
        }
    }
    // column sums -> T (pre-zeroed)
#pragma unroll
    for (int i = 0; i < 4; ++i)
        colred[t >> 4][hq + i] = acc[0][i] + acc[1][i];
    __syncthreads();
    if (t < H) {
        float s = 0.f;
#pragma unroll
        for (int g = 0; g < 16; ++g) s += colred[g][t];
        atomicAdd(&T[t], s);
    }
}

// ---- K2: stream bias row, scan-compact edges, 16-stream edge accumulation ----
__global__ __launch_bounds__(256) void k_main(const float* __restrict__ bias,
                                              const float* __restrict__ fts,
                                              const float* __restrict__ f1g,
                                              const float* __restrict__ f2g,
                                              const float* __restrict__ T,
                                              float* __restrict__ out) {
    __shared__ int   listN[MAXE];
    __shared__ float redW[16][64];
    __shared__ float redF[16][64];
    __shared__ float redE[16];
    __shared__ int wbase[4];
    __shared__ int s_cnt;
    const int t = threadIdx.x;
    const int m = blockIdx.x;
    const int lane = t & 63;
    const int w = t >> 6;
    const float f1m = f1g[m];

    // Phase A: 8 hoisted float4 loads -> count -> one scan -> compact writes
    const float4* brow = (const float4*)(bias + (size_t)m * N);
    float4 r[8];
#pragma unroll
    for (int i = 0; i < 8; ++i) r[i] = brow[t + i * 256];
    int c = 0;
#pragma unroll
    for (int i = 0; i < 8; ++i)
        c += (r[i].x == 0.f) + (r[i].y == 0.f) + (r[i].z == 0.f) + (r[i].w == 0.f);
    int sc = c;                                // wave inclusive scan
#pragma unroll
    for (int o = 1; o < 64; o <<= 1) {
        int u = __shfl_up(sc, o);
        if (lane >= o) sc += u;
    }
    if (lane == 63) wbase[w] = sc;
    __syncthreads();
    int base = 0;
#pragma unroll
    for (int ww = 0; ww < 4; ++ww) if (ww < w) base += wbase[ww];
    int pos = base + sc - c;                   // exclusive prefix
#pragma unroll
    for (int i = 0; i < 8; ++i) {
        int nb = (t + i * 256) * 4;
        if (r[i].x == 0.f) { if (pos < MAXE) listN[pos] = nb;     ++pos; }
        if (r[i].y == 0.f) { if (pos < MAXE) listN[pos] = nb + 1; ++pos; }
        if (r[i].z == 0.f) { if (pos < MAXE) listN[pos] = nb + 2; ++pos; }
        if (r[i].w == 0.f) { if (pos < MAXE) listN[pos] = nb + 3; ++pos; }
    }
    if (t == 255) s_cnt = pos;
    __syncthreads();
    const int cnt = s_cnt < MAXE ? s_cnt : MAXE;

    // Phase B: 16 streams (16-lane groups x float4 over h), depth-2 pipeline
    const int g = t >> 4;              // 0..15
    const int h4 = (t & 15) * 4;
    float4 aW = make_float4(0.f, 0.f, 0.f, 0.f);
    float4 aF = make_float4(0.f, 0.f, 0.f, 0.f);
    float aE = 0.f;
    int e = g;
    float4 v0 = make_float4(0.f, 0.f, 0.f, 0.f);
    float ff0 = 0.f;
    if (e < cnt) {
        int n = listN[e];
        v0 = *(const float4*)&fts[(size_t)n * H + h4];
        ff0 = f2g[n];
    }
    while (e < cnt) {
        int e1 = e + 16;
        float4 v1 = make_float4(0.f, 0.f, 0.f, 0.f);
        float ff1 = 0.f;
        if (e1 < cnt) {
            int n1 = listN[e1];
            v1 = *(const float4*)&fts[(size_t)n1 * H + h4];
            ff1 = f2g[n1];
        }
        float ee = __expf(fmaxf(f1m + ff0, 0.f));
        aW.x += ee * v0.x; aW.y += ee * v0.y; aW.z += ee * v0.z; aW.w += ee * v0.w;
        aF.x += v0.x;      aF.y += v0.y;      aF.z += v0.z;      aF.w += v0.w;
        aE += ee;
        v0 = v1; ff0 = ff1; e = e1;
    }
    *(float4*)&redW[g][h4] = aW;
    *(float4*)&redF[g][h4] = aF;
    if ((t & 15) == 0) redE[g] = aE;
    __syncthreads();

    if (t < H) {
        float eW = 0.f, eF = 0.f, eE = 0.f;
#pragma unroll
        for (int s = 0; s < 16; ++s) { eW += redW[s][t]; eF += redF[s][t]; eE += redE[s]; }
        float S = (cnt > 0) ? eW / eE : 0.f;
        float val = S - 9.0f * (T[t] - eF);
        out[(size_t)m * H + t] = val > 0.f ? val : expm1f(val);
    }
}

extern "C" void kernel_launch(void* const* d_in, const int* in_sizes, int n_in,
                              void* d_out, int out_size, void* d_ws, size_t ws_size,
                              hipStream_t stream) {
    const float* feat = (const float*)d_in[0];
    const float* bias = (const float*)d_in[1];
    const float* W    = (const float*)d_in[2];
    const float* a1   = (const float*)d_in[3];
    const float* b1   = (const float*)d_in[4];
    const float* a2   = (const float*)d_in[5];
    const float* b2   = (const float*)d_in[6];
    float* out = (float*)d_out;

    float* ws  = (float*)d_ws;
    float* fts = ws;                        // N*H
    float* f1  = fts + (size_t)N * H;       // N
    float* f2  = f1 + N;                    // N
    float* T   = f2 + N;                    // H

    hipMemsetAsync(T, 0, H * sizeof(float), stream);
    hipLaunchKernelGGL(k_fts,  dim3(N / 32), dim3(256), 0, stream,
                       feat, W, a1, b1, a2, b2, fts, f1, f2, T);
    hipLaunchKernelGGL(k_main, dim3(N), dim3(256), 0, stream,
                       bias, fts, f1, f2, T, out);
}